// Round 1
// baseline (81.554 us; speedup 1.0000x reference)
//
#include <hip/hip_runtime.h>

#define B 64
#define T 4096
#define AD 1024   // ATTN_RNN_DIM
#define HD 256    // HYPERNET_DIM
#define CH 32
#define KS 31
#define OD 128
#define PADW 15
#define CWN (CH*KS)   // 992
#define TILE_T 256

// ---------------- Kernel A: h[b,j] = tanh(dot(query[b,:], W1[j,:]) + b1[j])
// one wave per output element; 16384 waves -> 4096 blocks x 256 threads
__global__ __launch_bounds__(256) void k_hyper1(const float* __restrict__ q,
        const float* __restrict__ W1, const float* __restrict__ b1,
        float* __restrict__ h) {
    int wid  = blockIdx.x * 4 + (threadIdx.x >> 6);
    int lane = threadIdx.x & 63;
    int b = wid >> 8;          // 256 j per b
    int j = wid & 255;
    const float* qr = q  + (size_t)b * AD;
    const float* wr = W1 + (size_t)j * AD;
    float s = 0.f;
    #pragma unroll
    for (int m = 0; m < AD / 64; ++m) {
        int i = m * 64 + lane;
        s += qr[i] * wr[i];
    }
    #pragma unroll
    for (int off = 32; off > 0; off >>= 1)
        s += __shfl_down(s, off, 64);
    if (lane == 0) h[b * HD + j] = tanhf(s + b1[j]);
}

// ---------------- Kernel B: per-b: cw = h@W2^T + b2 ; Gt[b,k,o] = sum_c Wfc[o,c]*cw[c,k]
__global__ __launch_bounds__(256) void k_hyper2(const float* __restrict__ h,
        const float* __restrict__ W2, const float* __restrict__ b2,
        const float* __restrict__ Wfc, float* __restrict__ Gt) {
    int b = blockIdx.x;
    int tid = threadIdx.x;
    __shared__ float hs[HD];            // 256
    __shared__ float cws[CWN];          // 992
    __shared__ float wfs[OD * (CH + 1)];// 128*33, padded stride vs bank conflicts
    hs[tid] = h[(size_t)b * HD + tid];
    for (int idx = tid; idx < OD * CH; idx += 256) {
        int o = idx >> 5, c = idx & 31;
        wfs[o * (CH + 1) + c] = Wfc[idx];
    }
    __syncthreads();
    #pragma unroll
    for (int p = 0; p < 4; ++p) {
        int idx = p * 256 + tid;
        if (idx < CWN) {
            const float4* wr = (const float4*)(W2 + (size_t)idx * HD);
            float s = 0.f;
            #pragma unroll
            for (int m = 0; m < HD / 4; ++m) {
                float4 w = wr[m];
                s += w.x * hs[m*4+0] + w.y * hs[m*4+1]
                   + w.z * hs[m*4+2] + w.w * hs[m*4+3];
            }
            cws[idx] = s + b2[idx];
        }
    }
    __syncthreads();
    #pragma unroll
    for (int p = 0; p < 16; ++p) {
        int idx = p * 256 + tid;
        if (idx < KS * OD) {      // 3968
            int k = idx >> 7;     // / 128
            int o = idx & 127;
            float s = 0.f;
            #pragma unroll
            for (int c = 0; c < CH; ++c)
                s += wfs[o * (CH + 1) + c] * cws[c * KS + k];
            Gt[(size_t)b * (KS * OD) + idx] = s;
        }
    }
}

// ---------------- Kernel C: out[b,t,o] = sum_k Gt[b,k,o]*pa[b,t+k-15] + bfc[o]
// block = (b, 256-wide t tile); thread owns one o (tid&127), half the tile (tid>>7)
__global__ __launch_bounds__(256) void k_conv(const float* __restrict__ pa_g,
        const float* __restrict__ Gt, const float* __restrict__ bfc,
        float* __restrict__ out) {
    int b    = blockIdx.x >> 4;   // 16 tiles per b
    int tile = blockIdx.x & 15;
    int t0   = tile * TILE_T;
    int tid  = threadIdx.x;
    __shared__ float pa[TILE_T + 32];   // 288 floats (286 valid + 2 slack)
    {
        int g = t0 + tid - PADW;
        pa[tid] = (g >= 0 && g < T) ? pa_g[(size_t)b * T + g] : 0.f;
        if (tid < 32) {
            int i2 = 256 + tid;
            int g2 = t0 + i2 - PADW;
            pa[i2] = (g2 >= 0 && g2 < T) ? pa_g[(size_t)b * T + g2] : 0.f;
        }
    }
    __syncthreads();
    int o = tid & 127, half = tid >> 7;
    float g[KS];
    #pragma unroll
    for (int k = 0; k < KS; ++k) g[k] = Gt[(size_t)b * (KS * OD) + k * OD + o];
    float base = bfc[o];
    float* outb = out + ((size_t)b * T + t0) * OD + o;
    for (int c = 0; c < 16; ++c) {     // 16 chunks of 8 t's per half
        int s = half * 128 + c * 8;
        float pw[40];
        const float4* lp = (const float4*)(pa + s);   // s % 8 == 0 -> 32B aligned
        #pragma unroll
        for (int q4 = 0; q4 < 10; ++q4) {
            float4 v = lp[q4];
            pw[q4*4+0] = v.x; pw[q4*4+1] = v.y; pw[q4*4+2] = v.z; pw[q4*4+3] = v.w;
        }
        float acc[8];
        #pragma unroll
        for (int tt = 0; tt < 8; ++tt) acc[tt] = base;
        #pragma unroll
        for (int tt = 0; tt < 8; ++tt) {
            #pragma unroll
            for (int k = 0; k < KS; ++k)
                acc[tt] += g[k] * pw[tt + k];
        }
        #pragma unroll
        for (int tt = 0; tt < 8; ++tt)
            outb[(size_t)(s + tt) * OD] = acc[tt];
    }
}

extern "C" void kernel_launch(void* const* d_in, const int* in_sizes, int n_in,
                              void* d_out, int out_size, void* d_ws, size_t ws_size,
                              hipStream_t stream) {
    const float* query = (const float*)d_in[0];
    const float* prev  = (const float*)d_in[1];
    const float* W1    = (const float*)d_in[2];
    const float* b1    = (const float*)d_in[3];
    const float* W2    = (const float*)d_in[4];
    const float* b2    = (const float*)d_in[5];
    const float* Wfc   = (const float*)d_in[6];
    const float* bfc   = (const float*)d_in[7];
    float* out = (float*)d_out;

    float* h  = (float*)d_ws;          // 64*256 floats
    float* Gt = h + B * HD;            // 64*31*128 floats

    k_hyper1<<<dim3(4096), dim3(256), 0, stream>>>(query, W1, b1, h);
    k_hyper2<<<dim3(B), dim3(256), 0, stream>>>(h, W2, b2, Wfc, Gt);
    k_conv<<<dim3(B * (T / TILE_T)), dim3(256), 0, stream>>>(prev, Gt, bfc, out);
}

// Round 2
// 81.435 us; speedup vs baseline: 1.0015x; 1.0015x over previous
//
#include <hip/hip_runtime.h>

#define B 64
#define T 4096
#define AD 1024   // ATTN_RNN_DIM
#define HD 256    // HYPERNET_DIM
#define CH 32
#define KS 31
#define OD 128
#define PADW 15
#define CWN (CH*KS)   // 992
#define TILE_T 256

// ---------------- Kernel A: h[b,j] = tanh(dot(query[b,:], W1[j,:]) + b1[j])
// one wave per output element, float4 loads; 16384 waves -> 4096 blocks x 256
__global__ __launch_bounds__(256) void k_hyper1(const float* __restrict__ q,
        const float* __restrict__ W1, const float* __restrict__ b1,
        float* __restrict__ h) {
    int wid  = blockIdx.x * 4 + (threadIdx.x >> 6);
    int lane = threadIdx.x & 63;
    int b = wid >> 8;          // 256 j per b
    int j = wid & 255;
    const float4* qr = (const float4*)(q  + (size_t)b * AD);
    const float4* wr = (const float4*)(W1 + (size_t)j * AD);
    float s = 0.f;
    #pragma unroll
    for (int m = 0; m < 4; ++m) {
        float4 a = qr[m * 64 + lane];
        float4 w = wr[m * 64 + lane];
        s += a.x * w.x + a.y * w.y + a.z * w.z + a.w * w.w;
    }
    #pragma unroll
    for (int off = 32; off > 0; off >>= 1)
        s += __shfl_down(s, off, 64);
    if (lane == 0) h[b * HD + j] = tanhf(s + b1[j]);
}

// ---------------- Kernel B: cw[b,r] = dot(h[b,:], W2[r,:]) + b2[r]
// 4 blocks per b (256 blocks total), one 256-long row per thread
__global__ __launch_bounds__(256) void k_cw(const float* __restrict__ h,
        const float* __restrict__ W2, const float* __restrict__ b2,
        float* __restrict__ cw) {
    int b   = blockIdx.x >> 2;
    int qtr = blockIdx.x & 3;
    int tid = threadIdx.x;
    __shared__ float hs[HD];
    hs[tid] = h[(size_t)b * HD + tid];
    __syncthreads();
    int r = qtr * 248 + tid;
    if (tid < 248) {
        const float4* wr = (const float4*)(W2 + (size_t)r * HD);
        float s = 0.f;
        #pragma unroll
        for (int m = 0; m < HD / 4; ++m) {
            float4 w = wr[m];
            s += w.x * hs[4*m+0] + w.y * hs[4*m+1]
               + w.z * hs[4*m+2] + w.w * hs[4*m+3];
        }
        cw[(size_t)b * CWN + r] = s + b2[r];
    }
}

// ---------------- Kernel C: G[o,k] = sum_c Wfc[o,c]*cw[b,c,k]  (LDS prologue)
//                  out[b,t,o] = sum_k G[o,k]*pa[b,t+k-15] + bfc[o]
__global__ __launch_bounds__(256, 4) void k_conv(const float* __restrict__ pa_g,
        const float* __restrict__ cw, const float* __restrict__ Wfc,
        const float* __restrict__ bfc, float* __restrict__ out) {
    int b    = blockIdx.x >> 4;   // 16 tiles per b
    int tile = blockIdx.x & 15;
    int t0   = tile * TILE_T;
    int tid  = threadIdx.x;
    __shared__ float wfs_t[CH * OD];     // [c][o] transposed -> conflict-free reads
    __shared__ float cws[CWN];           // [c][k]
    __shared__ float Gl[KS * OD];        // [k][o]
    __shared__ float pa[TILE_T + 32];    // 288

    // stage Wfc transposed (one-time 32-way write conflict, negligible)
    #pragma unroll
    for (int p = 0; p < 16; ++p) {
        int idx = p * 256 + tid;
        int o = idx >> 5, c = idx & 31;
        wfs_t[c * OD + o] = Wfc[idx];
    }
    // stage cw[b]
    #pragma unroll
    for (int p = 0; p < 4; ++p) {
        int idx = p * 256 + tid;
        if (idx < CWN) cws[idx] = cw[(size_t)b * CWN + idx];
    }
    // stage prev_attn window
    {
        int g = t0 + tid - PADW;
        pa[tid] = (g >= 0 && g < T) ? pa_g[(size_t)b * T + g] : 0.f;
        if (tid < 32) {
            int i2 = 256 + tid, g2 = t0 + i2 - PADW;
            pa[i2] = (g2 >= 0 && g2 < T) ? pa_g[(size_t)b * T + g2] : 0.f;
        }
    }
    __syncthreads();
    // G[k,o] = sum_c wfs_t[c,o] * cws[c,k]
    #pragma unroll
    for (int p = 0; p < 16; ++p) {
        int idx = p * 256 + tid;
        if (idx < KS * OD) {
            int k = idx >> 7, o = idx & 127;
            float s = 0.f;
            #pragma unroll
            for (int c = 0; c < CH; ++c)
                s += wfs_t[c * OD + o] * cws[c * KS + k];
            Gl[idx] = s;
        }
    }
    __syncthreads();

    int o = tid & 127, half = tid >> 7;
    float g[KS];
    #pragma unroll
    for (int k = 0; k < KS; ++k) g[k] = Gl[k * OD + o];
    float base = bfc[o];
    float* outb = out + ((size_t)b * T + t0) * OD + o;
    for (int c = 0; c < 16; ++c) {       // 16 chunks of 8 t's per half
        int s0 = half * 128 + c * 8;
        float pw[40];
        const float4* lp = (const float4*)(pa + s0);  // 32B aligned
        #pragma unroll
        for (int q4 = 0; q4 < 10; ++q4) {
            float4 v = lp[q4];
            pw[q4*4+0] = v.x; pw[q4*4+1] = v.y; pw[q4*4+2] = v.z; pw[q4*4+3] = v.w;
        }
        float acc[8];
        #pragma unroll
        for (int tt = 0; tt < 8; ++tt) acc[tt] = base;
        #pragma unroll
        for (int tt = 0; tt < 8; ++tt) {
            #pragma unroll
            for (int k = 0; k < KS; ++k)
                acc[tt] += g[k] * pw[tt + k];
        }
        #pragma unroll
        for (int tt = 0; tt < 8; ++tt)
            outb[(size_t)(s0 + tt) * OD] = acc[tt];
    }
}

extern "C" void kernel_launch(void* const* d_in, const int* in_sizes, int n_in,
                              void* d_out, int out_size, void* d_ws, size_t ws_size,
                              hipStream_t stream) {
    const float* query = (const float*)d_in[0];
    const float* prev  = (const float*)d_in[1];
    const float* W1    = (const float*)d_in[2];
    const float* b1    = (const float*)d_in[3];
    const float* W2    = (const float*)d_in[4];
    const float* b2    = (const float*)d_in[5];
    const float* Wfc   = (const float*)d_in[6];
    const float* bfc   = (const float*)d_in[7];
    float* out = (float*)d_out;

    float* h  = (float*)d_ws;          // 64*256 floats
    float* cw = h + B * HD;            // 64*992 floats

    k_hyper1<<<dim3(4096), dim3(256), 0, stream>>>(query, W1, b1, h);
    k_cw    <<<dim3(B * 4), dim3(256), 0, stream>>>(h, W2, b2, cw);
    k_conv  <<<dim3(B * (T / TILE_T)), dim3(256), 0, stream>>>(prev, cw, Wfc, bfc, out);
}

// Round 3
// 77.370 us; speedup vs baseline: 1.0541x; 1.0525x over previous
//
#include <hip/hip_runtime.h>

#define B 64
#define T 4096
#define AD 1024   // ATTN_RNN_DIM
#define HD 256    // HYPERNET_DIM
#define CH 32
#define KS 31
#define OD 128
#define PADW 15
#define CWN (CH*KS)   // 992
#define TILE_T 128
#define NTILE (T / TILE_T)   // 32

// ---------------- Kernel A: h[b,j] = tanh(dot(query[b,:], W1[j,:]) + b1[j])
__global__ __launch_bounds__(256) void k_hyper1(const float* __restrict__ q,
        const float* __restrict__ W1, const float* __restrict__ b1,
        float* __restrict__ h) {
    int wid  = blockIdx.x * 4 + (threadIdx.x >> 6);
    int lane = threadIdx.x & 63;
    int b = wid >> 8;
    int j = wid & 255;
    const float4* qr = (const float4*)(q  + (size_t)b * AD);
    const float4* wr = (const float4*)(W1 + (size_t)j * AD);
    float s = 0.f;
    #pragma unroll
    for (int m = 0; m < 4; ++m) {
        float4 a = qr[m * 64 + lane];
        float4 w = wr[m * 64 + lane];
        s += a.x * w.x + a.y * w.y + a.z * w.z + a.w * w.w;
    }
    #pragma unroll
    for (int off = 32; off > 0; off >>= 1)
        s += __shfl_down(s, off, 64);
    if (lane == 0) h[b * HD + j] = tanhf(s + b1[j]);
}

// ---------------- Kernel B: cw[b,r] = dot(h[b,:], W2[r,:]) + b2[r]
__global__ __launch_bounds__(256) void k_cw(const float* __restrict__ h,
        const float* __restrict__ W2, const float* __restrict__ b2,
        float* __restrict__ cw) {
    int b   = blockIdx.x >> 2;
    int qtr = blockIdx.x & 3;
    int tid = threadIdx.x;
    __shared__ float hs[HD];
    hs[tid] = h[(size_t)b * HD + tid];
    __syncthreads();
    int r = qtr * 248 + tid;
    if (tid < 248) {
        const float4* wr = (const float4*)(W2 + (size_t)r * HD);
        float s = 0.f;
        #pragma unroll
        for (int m = 0; m < HD / 4; ++m) {
            float4 w = wr[m];
            s += w.x * hs[4*m+0] + w.y * hs[4*m+1]
               + w.z * hs[4*m+2] + w.w * hs[4*m+3];
        }
        cw[(size_t)b * CWN + r] = s + b2[r];
    }
}

// ---------------- Kernel C: Gt[b, k*OD+o] = sum_c Wfc[o,c]*cw[b, c*KS+k]
// 4 blocks per b; each block computes 992 G elements (4 per thread, tid<248)
__global__ __launch_bounds__(256) void k_G(const float* __restrict__ cw,
        const float* __restrict__ Wfc, float* __restrict__ Gt) {
    int b   = blockIdx.x >> 2;
    int qtr = blockIdx.x & 3;
    int tid = threadIdx.x;
    __shared__ float cws[CWN];
    __shared__ float wfs_t[CH * OD];   // [c][o]
    #pragma unroll
    for (int p = 0; p < 4; ++p) {
        int idx = p * 256 + tid;
        if (idx < CWN) cws[idx] = cw[(size_t)b * CWN + idx];
    }
    #pragma unroll
    for (int p = 0; p < 16; ++p) {
        int idx = p * 256 + tid;
        int o = idx >> 5, c = idx & 31;
        wfs_t[c * OD + o] = Wfc[idx];
    }
    __syncthreads();
    if (tid < 248) {
        int base = qtr * 992 + tid * 4;
        #pragma unroll
        for (int j = 0; j < 4; ++j) {
            int idx = base + j;
            int k = idx >> 7, o = idx & 127;
            float s = 0.f;
            #pragma unroll
            for (int c = 0; c < CH; ++c)
                s += wfs_t[c * OD + o] * cws[c * KS + k];
            Gt[(size_t)b * (KS * OD) + idx] = s;
        }
    }
}

// ---------------- Kernel D: out[b,t,o] = sum_k Gt[b,k,o]*pa[b,t+k-15] + bfc[o]
__device__ __forceinline__ void compute_chunk(const float* pa, int s0, float base,
                                              const float (&g)[KS], float (&acc)[8]) {
    float pw[40];
    const float4* lp = (const float4*)(pa + s0);   // s0 % 8 == 0 -> aligned
    #pragma unroll
    for (int q4 = 0; q4 < 10; ++q4) {
        float4 v = lp[q4];
        pw[q4*4+0] = v.x; pw[q4*4+1] = v.y; pw[q4*4+2] = v.z; pw[q4*4+3] = v.w;
    }
    #pragma unroll
    for (int tt = 0; tt < 8; ++tt) {
        float a = base;
        #pragma unroll
        for (int k = 0; k < KS; ++k)
            a += g[k] * pw[tt + k];
        acc[tt] = a;
    }
}

__device__ __forceinline__ void store_chunk(float* outb, int s0, const float (&acc)[8]) {
    #pragma unroll
    for (int tt = 0; tt < 8; ++tt)
        outb[(size_t)(s0 + tt) * OD] = acc[tt];
}

__global__ __launch_bounds__(256, 5) void k_conv(const float* __restrict__ pa_g,
        const float* __restrict__ Gt, const float* __restrict__ bfc,
        float* __restrict__ out) {
    // XCD-aware swizzle: grid 2048 = 8 XCDs x 256; keep a batch's tiles on one XCD
    int bid = blockIdx.x;
    int sid = (bid & 7) * 256 + (bid >> 3);
    int b    = sid >> 5;          // 32 tiles per b
    int tile = sid & 31;
    int t0   = tile * TILE_T;
    int tid  = threadIdx.x;
    __shared__ float Gl[KS * OD];        // 15.9 KB
    __shared__ float pa[TILE_T + 32];    // 160 floats

    #pragma unroll
    for (int p = 0; p < 16; ++p) {
        int idx = p * 256 + tid;
        if (idx < KS * OD) Gl[idx] = Gt[(size_t)b * (KS * OD) + idx];
    }
    if (tid < TILE_T + 32) {
        int g = t0 + tid - PADW;
        pa[tid] = (g >= 0 && g < T) ? pa_g[(size_t)b * T + g] : 0.f;
    }
    __syncthreads();

    int o = tid & 127, half = tid >> 7;
    float g[KS];
    #pragma unroll
    for (int k = 0; k < KS; ++k) g[k] = Gl[k * OD + o];
    float base = bfc[o];
    float* outb = out + ((size_t)b * T + t0) * OD + o;
    int h0 = half * 64;

    // software-pipelined: stores of chunk c drain under compute of chunk c+1
    float accA[8], accB[8];
    compute_chunk(pa, h0 + 0*8, base, g, accA);
    compute_chunk(pa, h0 + 1*8, base, g, accB);
    store_chunk(outb, h0 + 0*8, accA);
    compute_chunk(pa, h0 + 2*8, base, g, accA);
    store_chunk(outb, h0 + 1*8, accB);
    compute_chunk(pa, h0 + 3*8, base, g, accB);
    store_chunk(outb, h0 + 2*8, accA);
    compute_chunk(pa, h0 + 4*8, base, g, accA);
    store_chunk(outb, h0 + 3*8, accB);
    compute_chunk(pa, h0 + 5*8, base, g, accB);
    store_chunk(outb, h0 + 4*8, accA);
    compute_chunk(pa, h0 + 6*8, base, g, accA);
    store_chunk(outb, h0 + 5*8, accB);
    compute_chunk(pa, h0 + 7*8, base, g, accB);
    store_chunk(outb, h0 + 6*8, accA);
    store_chunk(outb, h0 + 7*8, accB);
}

extern "C" void kernel_launch(void* const* d_in, const int* in_sizes, int n_in,
                              void* d_out, int out_size, void* d_ws, size_t ws_size,
                              hipStream_t stream) {
    const float* query = (const float*)d_in[0];
    const float* prev  = (const float*)d_in[1];
    const float* W1    = (const float*)d_in[2];
    const float* b1    = (const float*)d_in[3];
    const float* W2    = (const float*)d_in[4];
    const float* b2    = (const float*)d_in[5];
    const float* Wfc   = (const float*)d_in[6];
    const float* bfc   = (const float*)d_in[7];
    float* out = (float*)d_out;

    float* h  = (float*)d_ws;          // 16384 floats
    float* cw = h + B * HD;            // 63488 floats
    float* Gt = cw + B * CWN;          // 253952 floats

    k_hyper1<<<dim3(4096), dim3(256), 0, stream>>>(query, W1, b1, h);
    k_cw    <<<dim3(B * 4), dim3(256), 0, stream>>>(h, W2, b2, cw);
    k_G     <<<dim3(B * 4), dim3(256), 0, stream>>>(cw, Wfc, Gt);
    k_conv  <<<dim3(B * NTILE), dim3(256), 0, stream>>>(prev, Gt, bfc, out);
}